// Round 3
// baseline (2220.982 us; speedup 1.0000x reference)
//
#include <hip/hip_runtime.h>
#include <hip/hip_bf16.h>
#include <math.h>

using bf16 = __hip_bfloat16;
typedef __bf16 bf16x8 __attribute__((ext_vector_type(8)));
typedef float f32x4 __attribute__((ext_vector_type(4)));

static constexpr int TOK = 16 * 56 * 56;   // 50176 tokens
static constexpr int CDIM = 384;
static constexpr float SCALE = 0.17677669529663687f; // 32^-0.5

// ---------------- weight transpose fp32 [K,N] -> bf16 [N,K] ----------------
__global__ void k_transpose(const float* __restrict__ in, bf16* __restrict__ out,
                            int K, int N) {
    int idx = blockIdx.x * 256 + threadIdx.x;
    if (idx >= K * N) return;
    int k = idx / N, n = idx - k * N;
    out[(size_t)n * K + k] = __float2bfloat16(in[idx]);
}

// ---------------- LayerNorm (+ optional roll + window partition) ----------------
__global__ __launch_bounds__(256) void k_ln(const float* __restrict__ src,
                                            const float* __restrict__ g,
                                            const float* __restrict__ bta,
                                            bf16* __restrict__ out,
                                            int shift, int windowed) {
    int wave = threadIdx.x >> 6, l = threadIdx.x & 63;
    int t = blockIdx.x * 4 + wave;
    int srow;
    if (windowed) {
        int wi = t / 49, n = t - wi * 49;
        int b_ = wi >> 6, w64 = wi & 63;
        int wy = w64 >> 3, wx = w64 & 7;
        int pin = n / 7, qin = n - pin * 7;
        int hs = wy * 7 + pin + shift; if (hs >= 56) hs -= 56;
        int ws2 = wx * 7 + qin + shift; if (ws2 >= 56) ws2 -= 56;
        srow = b_ * 3136 + hs * 56 + ws2;
    } else {
        srow = t;
    }
    const float* xr = src + (size_t)srow * CDIM;
    float v[6];
    float s = 0.f;
#pragma unroll
    for (int j = 0; j < 6; j++) { v[j] = xr[j * 64 + l]; s += v[j]; }
#pragma unroll
    for (int off = 32; off; off >>= 1) s += __shfl_xor(s, off, 64);
    float mean = s * (1.f / 384.f);
    float sq = 0.f;
#pragma unroll
    for (int j = 0; j < 6; j++) { float d = v[j] - mean; sq += d * d; }
#pragma unroll
    for (int off = 32; off; off >>= 1) sq += __shfl_xor(sq, off, 64);
    float rstd = rsqrtf(sq * (1.f / 384.f) + 1e-5f);
    bf16* op = out + (size_t)t * CDIM;
#pragma unroll
    for (int j = 0; j < 6; j++) {
        int c = j * 64 + l;
        float val = (v[j] - mean) * rstd * g[c] + bta[c];
        op[c] = __float2bfloat16(val);
    }
}

// ---------------- MFMA GEMM: register-direct, LDS-free, barrier-free ----------
// K is small (384/1536) and all operands are XCD-L2-resident (panel swizzle,
// FETCH=25MB measured == ideal), so the MFMA fragments are loaded straight
// from global: lane (q=l>>4, r=l&15) reads row r's 16B chunk q -> a wave-load
// touches 16 full 64B lines (row stride 768/3072B is 64B-aligned), zero
// overfetch. No LDS, no barriers: TLP (no-LDS occupancy) + compiler hoisting
// of next-step loads over current-step MFMAs hides the L2 latency.
#define GM_QKV    0
#define GM_PROJ   1
#define GM_FC1    2
#define GM_FC2    3
#define GM_FC2OUT 4

__global__ __launch_bounds__(256) void k_gemm(
    const bf16* __restrict__ A, const bf16* __restrict__ Bt,
    const float* __restrict__ bias, int K, int Nout,
    bf16* __restrict__ obf, float* __restrict__ xres, float* __restrict__ ofinal,
    const float* __restrict__ shortcut,
    int mode, int shift, int m_base) {
    int tid = threadIdx.x;
    int w = tid >> 6, l = tid & 63;

    // XCD-chunked, panel-major swizzle (bijective). Keeps all N-tiles of one
    // A-panel consecutive on one XCD -> A/B loads are that XCD's L2 hits.
    int nx = gridDim.x, ny = gridDim.y;
    int nwg = nx * ny;
    int bid = blockIdx.y * nx + blockIdx.x;     // dispatch order (x fastest)
    int xcd = bid & 7, slot = bid >> 3;
    int qch = nwg >> 3, rch = nwg & 7;
    int wk = (xcd < rch ? xcd * (qch + 1) : rch * (qch + 1) + (xcd - rch) * qch)
             + slot;
    int bx = wk / ny, by = wk - bx * ny;
    int m0 = bx * 128, n0 = by * 128;

    int wm = (w >> 1) * 64, wn = (w & 1) * 64;
    int q = l >> 4, r = l & 15;

    // per-lane 32-bit element offsets (uniform parts stay scalar)
    int aoff = (m0 + wm + r) * K + q * 8;
    int boff = (n0 + wn + r) * K + q * 8;

    f32x4 acc[4][4];
#pragma unroll
    for (int i = 0; i < 4; i++)
#pragma unroll
        for (int j = 0; j < 4; j++) acc[i][j] = f32x4{0.f, 0.f, 0.f, 0.f};

#pragma unroll 2
    for (int kt = 0; kt < K; kt += 32) {
        bf16x8 af[4], bfr[4];
#pragma unroll
        for (int mi = 0; mi < 4; mi++)
            af[mi] = *(const bf16x8*)(A + (size_t)(aoff + mi * 16 * K + kt));
#pragma unroll
        for (int ni = 0; ni < 4; ni++)
            bfr[ni] = *(const bf16x8*)(Bt + (size_t)(boff + ni * 16 * K + kt));
#pragma unroll
        for (int mi = 0; mi < 4; mi++)
#pragma unroll
            for (int ni = 0; ni < 4; ni++)
                acc[mi][ni] = __builtin_amdgcn_mfma_f32_16x16x32_bf16(
                    af[mi], bfr[ni], acc[mi][ni], 0, 0, 0);
    }

    // epilogue: C/D layout col = lane&15, row = (lane>>4)*4 + reg
#pragma unroll
    for (int mi = 0; mi < 4; mi++) {
#pragma unroll
        for (int ni = 0; ni < 4; ni++) {
#pragma unroll
            for (int rr = 0; rr < 4; rr++) {
                int grow = m0 + wm + mi * 16 + q * 4 + rr;  // chunk-local row
                int gcol = n0 + wn + ni * 16 + r;
                float v = acc[mi][ni][rr] + bias[gcol];
                if (mode == GM_QKV) {
                    obf[(size_t)grow * Nout + gcol] = __float2bfloat16(v);
                } else if (mode == GM_FC1) {
                    // tanh-form GELU: |err| < 4e-4 vs exact erf form, far
                    // below the bf16 rounding applied to this buffer anyway.
                    float u = v * (0.7978845608028654f
                                   + 0.0356774081363001f * v * v);
                    float t = 1.f - 2.f / (1.f + __expf(2.f * u));
                    v = 0.5f * v * (1.f + t);
                    obf[(size_t)grow * Nout + gcol] = __float2bfloat16(v);
                } else if (mode == GM_PROJ) {
                    int growg = m_base + grow;
                    int wi = growg / 49, n = growg - wi * 49;
                    int b_ = wi >> 6, w64 = wi & 63;
                    int wy = w64 >> 3, wx = w64 & 7;
                    int pin = n / 7, qin = n - pin * 7;
                    int hs = wy * 7 + pin + shift; if (hs >= 56) hs -= 56;
                    int ws2 = wx * 7 + qin + shift; if (ws2 >= 56) ws2 -= 56;
                    size_t t = (size_t)b_ * 3136 + hs * 56 + ws2;
                    xres[t * CDIM + gcol] = shortcut[t * CDIM + gcol] + v;
                } else {
                    size_t idx = (size_t)(m_base + grow) * CDIM + gcol;
                    float s2 = xres[idx] + v;
                    if (mode == GM_FC2) xres[idx] = s2;
                    else ofinal[idx] = s2;     // final output is fp32
                }
            }
        }
    }
}

// ---------------- windowed attention v2: wave per (window,head), 4 waves/block ----
__device__ __forceinline__ int regionof(int p) {
    return (p < 49) ? 0 : (p < 53 ? 1 : 2);
}

__global__ __launch_bounds__(256) void k_attn(const bf16* __restrict__ qkv,
                                              const float* __restrict__ rpb,
                                              bf16* __restrict__ out, int shift,
                                              int wi0) {
    __shared__ float kv[4][2][49 * 32];   // [wave][k/v] = 50176 B total
    int wave = threadIdx.x >> 6, l = threadIdx.x & 63;
    int p = blockIdx.x * 4 + wave;        // chunk-local (window,head) pair
    int wl = p / 12, h = p - wl * 12;
    int wig = wi0 + wl;
    float* ks = kv[wave][0];
    float* vs = kv[wave][1];

    const bf16* base = qkv + (size_t)wl * 49 * 1152 + h * 32;
#pragma unroll
    for (int it = 0; it < 25; it++) {
        int idx = l + it * 64;
        if (idx < 1568) {
            int n = idx >> 5, d = idx & 31;
            size_t ro = (size_t)n * 1152 + d;
            ks[idx] = __bfloat162float(base[ro + 384]);
            vs[idx] = __bfloat162float(base[ro + 768]);
        }
    }
    int active = (l < 49);
    int le = active ? l : 0;
    float qreg[32];
    const bf16* qrow = base + (size_t)le * 1152;
#pragma unroll
    for (int d = 0; d < 32; d++) qreg[d] = __bfloat162float(qrow[d]) * SCALE;
    __syncthreads();

    int pin = le / 7, qin = le - (le / 7) * 7;
    int w64 = wig & 63;
    int py = (w64 >> 3) * 7, px = (w64 & 7) * 7;
    int regq = regionof(py + pin) * 3 + regionof(px + qin);

    float srow[49];
    float mx = -1e30f;
#pragma unroll
    for (int m = 0; m < 49; m++) {
        const float* kr = &ks[m * 32];
        float s = 0.f;
#pragma unroll
        for (int d = 0; d < 32; d++) s += qreg[d] * kr[d];
        const int mp = m / 7, mq = m - (m / 7) * 7;
        s += rpb[((pin - mp + 6) * 13 + (qin - mq + 6)) * 12 + h];
        if (shift > 0) {
            int regm = regionof(py + mp) * 3 + regionof(px + mq);
            if (regm != regq) s -= 100.f;
        }
        srow[m] = s;
        mx = fmaxf(mx, s);
    }
    float sum = 0.f;
#pragma unroll
    for (int m = 0; m < 49; m++) {
        float e = __expf(srow[m] - mx);
        srow[m] = e;
        sum += e;
    }
    float inv = 1.f / sum;

    float o[32];
#pragma unroll
    for (int d = 0; d < 32; d++) o[d] = 0.f;
#pragma unroll
    for (int m = 0; m < 49; m++) {
        const float* vr = &vs[m * 32];
        float pm = srow[m];
#pragma unroll
        for (int d = 0; d < 32; d++) o[d] += pm * vr[d];
    }
    if (active) {
        bf16* op = out + ((size_t)wl * 49 + l) * 384 + h * 32;
#pragma unroll
        for (int d = 0; d < 32; d++) op[d] = __float2bfloat16(o[d] * inv);
    }
}

// ---------------- host launch ----------------
extern "C" void kernel_launch(void* const* d_in, const int* in_sizes, int n_in,
                              void* d_out, int out_size, void* d_ws, size_t ws_size,
                              hipStream_t stream) {
    const float* x       = (const float*)d_in[0];
    const float* norm1_g = (const float*)d_in[1];
    const float* norm1_b = (const float*)d_in[2];
    const float* qkv_w   = (const float*)d_in[3];
    const float* qkv_b   = (const float*)d_in[4];
    const float* rpb     = (const float*)d_in[5];
    const float* proj_w  = (const float*)d_in[6];
    const float* proj_b  = (const float*)d_in[7];
    const float* norm2_g = (const float*)d_in[8];
    const float* norm2_b = (const float*)d_in[9];
    const float* fc1_w   = (const float*)d_in[10];
    const float* fc1_b   = (const float*)d_in[11];
    const float* fc2_w   = (const float*)d_in[12];
    const float* fc2_b   = (const float*)d_in[13];
    (void)in_sizes; (void)n_in; (void)out_size;

    int nc = (ws_size >= (size_t)199753728) ? 2 : 4;
    int rows = TOK / nc;               // 25088 or 12544
    int wins = rows / 49;              // 512 or 256
    size_t arena_sz = (size_t)rows * 1152 * 2 + (size_t)rows * 384 * 2;

    float* xres  = (float*)d_ws;                              // 77,070,336 B
    bf16* lnbuf  = (bf16*)((char*)d_ws + 77070336);           // 38,535,168 B
    char* arena  = (char*)d_ws + 115605504;                   // arena_sz B
    bf16* wT     = (bf16*)((char*)d_ws + 115605504 + arena_sz); // 7,077,888 B

    bf16* qkvbuf  = (bf16*)arena;
    bf16* attnbuf = (bf16*)(arena + (size_t)rows * 1152 * 2);
    bf16* fc1buf  = (bf16*)arena;     // rows*1536*2 <= rows*1152*2 + rows*384*2

    bf16* qkvT  = wT;                          // 2 x 1152*384
    bf16* projT = wT + 884736;                 // 2 x 384*384
    bf16* fc1T  = projT + 294912;              // 2 x 1536*384
    bf16* fc2T  = fc1T + 1179648;              // 2 x 384*1536

    for (int i = 0; i < 2; i++) {
        k_transpose<<<(384 * 1152 + 255) / 256, 256, 0, stream>>>(
            qkv_w + (size_t)i * 442368, qkvT + (size_t)i * 442368, 384, 1152);
        k_transpose<<<(384 * 384 + 255) / 256, 256, 0, stream>>>(
            proj_w + (size_t)i * 147456, projT + (size_t)i * 147456, 384, 384);
        k_transpose<<<(384 * 1536 + 255) / 256, 256, 0, stream>>>(
            fc1_w + (size_t)i * 589824, fc1T + (size_t)i * 589824, 384, 1536);
        k_transpose<<<(1536 * 384 + 255) / 256, 256, 0, stream>>>(
            fc2_w + (size_t)i * 589824, fc2T + (size_t)i * 589824, 1536, 384);
    }

    for (int i = 0; i < 2; i++) {
        int shift = (i == 0) ? 0 : 3;
        // block 0 reads the input x directly (xres not yet materialized);
        // proj's epilogue then writes xres = x + o, eliminating the k_cvt copy.
        const float* resid = (i == 0) ? x : xres;
        k_ln<<<TOK / 4, 256, 0, stream>>>(resid, norm1_g + i * 384, norm1_b + i * 384,
                                          lnbuf, shift, 1);
        for (int c = 0; c < nc; c++) {
            const bf16* Ac = lnbuf + (size_t)c * rows * 384;
            k_gemm<<<dim3(rows / 128, 9), 256, 0, stream>>>(
                Ac, qkvT + (size_t)i * 442368, qkv_b + i * 1152, 384, 1152,
                qkvbuf, nullptr, nullptr, nullptr, GM_QKV, 0, 0);
            k_attn<<<wins * 12 / 4, 256, 0, stream>>>(qkvbuf, rpb + i * 2028,
                                                      attnbuf, shift, c * wins);
            k_gemm<<<dim3(rows / 128, 3), 256, 0, stream>>>(
                attnbuf, projT + (size_t)i * 147456, proj_b + i * 384, 384, 384,
                nullptr, xres, nullptr, resid, GM_PROJ, shift, c * rows);
        }
        k_ln<<<TOK / 4, 256, 0, stream>>>(xres, norm2_g + i * 384, norm2_b + i * 384,
                                          lnbuf, 0, 0);
        for (int c = 0; c < nc; c++) {
            const bf16* Ac = lnbuf + (size_t)c * rows * 384;
            k_gemm<<<dim3(rows / 128, 12), 256, 0, stream>>>(
                Ac, fc1T + (size_t)i * 589824, fc1_b + i * 1536, 384, 1536,
                fc1buf, nullptr, nullptr, nullptr, GM_FC1, 0, 0);
            k_gemm<<<dim3(rows / 128, 3), 256, 0, stream>>>(
                fc1buf, fc2T + (size_t)i * 589824, fc2_b + i * 384, 1536, 384,
                nullptr, xres, (float*)d_out, nullptr,
                (i == 0) ? GM_FC2 : GM_FC2OUT, 0, c * rows);
        }
    }
}

// Round 4
// 1469.144 us; speedup vs baseline: 1.5118x; 1.5118x over previous
//
#include <hip/hip_runtime.h>
#include <hip/hip_bf16.h>
#include <math.h>

using bf16 = __hip_bfloat16;
typedef __bf16 bf16x8 __attribute__((ext_vector_type(8)));
typedef float f32x4 __attribute__((ext_vector_type(4)));

static constexpr int TOK = 16 * 56 * 56;   // 50176 tokens
static constexpr int CDIM = 384;
static constexpr float SCALE = 0.17677669529663687f; // 32^-0.5

// ---------------- weight transpose fp32 [K,N] -> bf16 [N,K] ----------------
__global__ void k_transpose(const float* __restrict__ in, bf16* __restrict__ out,
                            int K, int N) {
    int idx = blockIdx.x * 256 + threadIdx.x;
    if (idx >= K * N) return;
    int k = idx / N, n = idx - k * N;
    out[(size_t)n * K + k] = __float2bfloat16(in[idx]);
}

// ---------------- LayerNorm (+ optional roll + window partition) ----------------
__global__ __launch_bounds__(256) void k_ln(const float* __restrict__ src,
                                            const float* __restrict__ g,
                                            const float* __restrict__ bta,
                                            bf16* __restrict__ out,
                                            int shift, int windowed) {
    int wave = threadIdx.x >> 6, l = threadIdx.x & 63;
    int t = blockIdx.x * 4 + wave;
    int srow;
    if (windowed) {
        int wi = t / 49, n = t - wi * 49;
        int b_ = wi >> 6, w64 = wi & 63;
        int wy = w64 >> 3, wx = w64 & 7;
        int pin = n / 7, qin = n - pin * 7;
        int hs = wy * 7 + pin + shift; if (hs >= 56) hs -= 56;
        int ws2 = wx * 7 + qin + shift; if (ws2 >= 56) ws2 -= 56;
        srow = b_ * 3136 + hs * 56 + ws2;
    } else {
        srow = t;
    }
    const float* xr = src + (size_t)srow * CDIM;
    float v[6];
    float s = 0.f;
#pragma unroll
    for (int j = 0; j < 6; j++) { v[j] = xr[j * 64 + l]; s += v[j]; }
#pragma unroll
    for (int off = 32; off; off >>= 1) s += __shfl_xor(s, off, 64);
    float mean = s * (1.f / 384.f);
    float sq = 0.f;
#pragma unroll
    for (int j = 0; j < 6; j++) { float d = v[j] - mean; sq += d * d; }
#pragma unroll
    for (int off = 32; off; off >>= 1) sq += __shfl_xor(sq, off, 64);
    float rstd = rsqrtf(sq * (1.f / 384.f) + 1e-5f);
    bf16* op = out + (size_t)t * CDIM;
#pragma unroll
    for (int j = 0; j < 6; j++) {
        int c = j * 64 + l;
        float val = (v[j] - mean) * rstd * g[c] + bta[c];
        op[c] = __float2bfloat16(val);
    }
}

// ---------------- MFMA GEMM: 2-phase LDS pipeline + vectorized epilogue ------
#define GM_QKV    0
#define GM_PROJ   1
#define GM_FC1    2
#define GM_FC2    3
#define GM_FC2OUT 4

__device__ __forceinline__ void gld16(const void* g, void* l) {
    __builtin_amdgcn_global_load_lds(
        (const __attribute__((address_space(1))) void*)g,
        (__attribute__((address_space(3))) void*)l, 16, 0, 0);
}

__device__ __forceinline__ void store4bf(bf16* p, f32x4 v) {
    union { unsigned short us[4]; uint2 u2; } pk;
#pragma unroll
    for (int i = 0; i < 4; i++) {
        __hip_bfloat16 h = __float2bfloat16(v[i]);
        pk.us[i] = *reinterpret_cast<unsigned short*>(&h);
    }
    *reinterpret_cast<uint2*>(p) = pk.u2;
}

__global__ __launch_bounds__(256) void k_gemm(
    const bf16* __restrict__ A, const bf16* __restrict__ Bt,
    const float* __restrict__ bias, int K, int Nout,
    bf16* __restrict__ obf, float* __restrict__ xres, float* __restrict__ ofinal,
    const float* __restrict__ shortcut,
    int mode, int shift, int m_base) {
    __shared__ __align__(16) bf16 As[2][128 * 32];
    __shared__ __align__(16) bf16 Bs[2][128 * 32];
    int tid = threadIdx.x;
    int w = tid >> 6, l = tid & 63;

    // XCD-chunked, panel-major swizzle (bijective): all N-tiles of one A-panel
    // run consecutively on one XCD -> A/B staging loads are that XCD's L2 hits
    // (verified: FETCH dropped 80MB -> 25MB == ideal).
    int nx = gridDim.x, ny = gridDim.y;
    int nwg = nx * ny;
    int bid = blockIdx.y * nx + blockIdx.x;     // dispatch order (x fastest)
    int xcd = bid & 7, slot = bid >> 3;
    int qch = nwg >> 3, rch = nwg & 7;
    int wk = (xcd < rch ? xcd * (qch + 1) : rch * (qch + 1) + (xcd - rch) * qch)
             + slot;
    int bx = wk / ny, by = wk - bx * ny;
    int m0 = bx * 128, n0 = by * 128;

    int wm = (w >> 1) * 64, wn = (w & 1) * 64;

    f32x4 acc[4][4];
#pragma unroll
    for (int i = 0; i < 4; i++)
#pragma unroll
        for (int j = 0; j < 4; j++) acc[i][j] = f32x4{0.f, 0.f, 0.f, 0.f};

    // staging: 512 slots of 16B per matrix; thread t handles slots t, t+256
    int s0 = tid, s1 = tid + 256;
    int ar0 = s0 >> 2, ac0 = (s0 & 3) * 8;
    int ar1 = s1 >> 2, ac1 = (s1 & 3) * 8;
    const bf16* Ag0 = A + (size_t)(m0 + ar0) * K + ac0;
    const bf16* Ag1 = A + (size_t)(m0 + ar1) * K + ac1;
    const bf16* Bg0 = Bt + (size_t)(n0 + ar0) * K + ac0;
    const bf16* Bg1 = Bt + (size_t)(n0 + ar1) * K + ac1;
    char* asb[2] = { (char*)&As[0][0] + (size_t)(w * 64) * 16,
                     (char*)&As[1][0] + (size_t)(w * 64) * 16 };
    char* bsb[2] = { (char*)&Bs[0][0] + (size_t)(w * 64) * 16,
                     (char*)&Bs[1][0] + (size_t)(w * 64) * 16 };

    int q = l >> 4, r = l & 15;

    auto stage = [&](int buf, int kt) {
        int kk = kt * 32;
        gld16(Ag0 + kk, asb[buf]);
        gld16(Ag1 + kk, asb[buf] + 4096);
        gld16(Bg0 + kk, bsb[buf]);
        gld16(Bg1 + kk, bsb[buf] + 4096);
    };
    // NOTE operand order: mfma(bfr, af) so the C/D "row" dim is the B-side.
    // Lane (q,r) then holds output row wm+mi*16+r, cols wn+ni*16+q*4..+3 —
    // 4 CONSECUTIVE columns -> vectorized epilogue stores.
    auto compute = [&](int buf) {
        const bf16* Ax = &As[buf][0];
        const bf16* Bx = &Bs[buf][0];
        bf16x8 af[4], bfr[4];
#pragma unroll
        for (int mi = 0; mi < 4; mi++)
            af[mi] = *(const bf16x8*)&Ax[(wm + mi * 16 + r) * 32 + q * 8];
#pragma unroll
        for (int ni = 0; ni < 4; ni++)
            bfr[ni] = *(const bf16x8*)&Bx[(wn + ni * 16 + r) * 32 + q * 8];
#pragma unroll
        for (int mi = 0; mi < 4; mi++)
#pragma unroll
            for (int ni = 0; ni < 4; ni++)
                acc[mi][ni] = __builtin_amdgcn_mfma_f32_16x16x32_bf16(
                    bfr[ni], af[mi], acc[mi][ni], 0, 0, 0);
    };

    const int nk = K >> 5;                 // 12 or 48, always even
    stage(0, 0);
    asm volatile("s_waitcnt vmcnt(0)" ::: "memory");
    __builtin_amdgcn_s_barrier();
    for (int t = 0; t < nk; t += 2) {
        stage(1, t + 1);               // issue next tile
        compute(0);                    // latency hides under this
        asm volatile("s_waitcnt vmcnt(0)" ::: "memory");
        __builtin_amdgcn_s_barrier();
        if (t + 2 < nk) stage(0, t + 2);
        compute(1);
        asm volatile("s_waitcnt vmcnt(0)" ::: "memory");
        __builtin_amdgcn_s_barrier();
    }

    // epilogue: row = wm+mi*16+r (4 rows/thread), cols = wn+ni*16+q*4..+3
#pragma unroll
    for (int mi = 0; mi < 4; mi++) {
        int grow = m0 + wm + mi * 16 + r;       // chunk-local output row
        size_t rowbase;
        if (mode == GM_PROJ) {
            int growg = m_base + grow;
            int wi = growg / 49, n = growg - wi * 49;
            int b_ = wi >> 6, w64 = wi & 63;
            int wy = w64 >> 3, wx = w64 & 7;
            int pin = n / 7, qin = n - pin * 7;
            int hs = wy * 7 + pin + shift; if (hs >= 56) hs -= 56;
            int ws2 = wx * 7 + qin + shift; if (ws2 >= 56) ws2 -= 56;
            rowbase = ((size_t)b_ * 3136 + hs * 56 + ws2) * CDIM;
        } else if (mode == GM_QKV || mode == GM_FC1) {
            rowbase = (size_t)grow * Nout;
        } else {
            rowbase = (size_t)(m_base + grow) * CDIM;
        }
#pragma unroll
        for (int ni = 0; ni < 4; ni++) {
            int gc0 = n0 + wn + ni * 16 + q * 4;
            const f32x4 bv = *(const f32x4*)&bias[gc0];
            f32x4 vv;
#pragma unroll
            for (int rr = 0; rr < 4; rr++) vv[rr] = acc[mi][ni][rr] + bv[rr];
            if (mode == GM_QKV) {
                store4bf(obf + rowbase + gc0, vv);
            } else if (mode == GM_FC1) {
#pragma unroll
                for (int rr = 0; rr < 4; rr++) {
                    float v = vv[rr];
                    // tanh-form GELU: |err| < 4e-4, below bf16 rounding.
                    float u = v * (0.7978845608028654f
                                   + 0.0356774081363001f * v * v);
                    float t = 1.f - 2.f / (1.f + __expf(2.f * u));
                    vv[rr] = 0.5f * v * (1.f + t);
                }
                store4bf(obf + rowbase + gc0, vv);
            } else if (mode == GM_PROJ) {
                const f32x4 sc = *(const f32x4*)(shortcut + rowbase + gc0);
#pragma unroll
                for (int rr = 0; rr < 4; rr++) vv[rr] += sc[rr];
                *(f32x4*)(xres + rowbase + gc0) = vv;
            } else {
                const f32x4 old = *(const f32x4*)(xres + rowbase + gc0);
#pragma unroll
                for (int rr = 0; rr < 4; rr++) vv[rr] += old[rr];
                if (mode == GM_FC2) *(f32x4*)(xres + rowbase + gc0) = vv;
                else *(f32x4*)(ofinal + rowbase + gc0) = vv;  // fp32 final out
            }
        }
    }
}

// ---------------- windowed attention v2: wave per (window,head), 4 waves/block ----
__device__ __forceinline__ int regionof(int p) {
    return (p < 49) ? 0 : (p < 53 ? 1 : 2);
}

__global__ __launch_bounds__(256) void k_attn(const bf16* __restrict__ qkv,
                                              const float* __restrict__ rpb,
                                              bf16* __restrict__ out, int shift,
                                              int wi0) {
    __shared__ float kv[4][2][49 * 32];   // [wave][k/v] = 50176 B total
    int wave = threadIdx.x >> 6, l = threadIdx.x & 63;
    int p = blockIdx.x * 4 + wave;        // chunk-local (window,head) pair
    int wl = p / 12, h = p - wl * 12;
    int wig = wi0 + wl;
    float* ks = kv[wave][0];
    float* vs = kv[wave][1];

    const bf16* base = qkv + (size_t)wl * 49 * 1152 + h * 32;
#pragma unroll
    for (int it = 0; it < 25; it++) {
        int idx = l + it * 64;
        if (idx < 1568) {
            int n = idx >> 5, d = idx & 31;
            size_t ro = (size_t)n * 1152 + d;
            ks[idx] = __bfloat162float(base[ro + 384]);
            vs[idx] = __bfloat162float(base[ro + 768]);
        }
    }
    int active = (l < 49);
    int le = active ? l : 0;
    float qreg[32];
    const bf16* qrow = base + (size_t)le * 1152;
#pragma unroll
    for (int d = 0; d < 32; d++) qreg[d] = __bfloat162float(qrow[d]) * SCALE;
    __syncthreads();

    int pin = le / 7, qin = le - (le / 7) * 7;
    int w64 = wig & 63;
    int py = (w64 >> 3) * 7, px = (w64 & 7) * 7;
    int regq = regionof(py + pin) * 3 + regionof(px + qin);

    float srow[49];
    float mx = -1e30f;
#pragma unroll
    for (int m = 0; m < 49; m++) {
        const float* kr = &ks[m * 32];
        float s = 0.f;
#pragma unroll
        for (int d = 0; d < 32; d++) s += qreg[d] * kr[d];
        const int mp = m / 7, mq = m - (m / 7) * 7;
        s += rpb[((pin - mp + 6) * 13 + (qin - mq + 6)) * 12 + h];
        if (shift > 0) {
            int regm = regionof(py + mp) * 3 + regionof(px + mq);
            if (regm != regq) s -= 100.f;
        }
        srow[m] = s;
        mx = fmaxf(mx, s);
    }
    float sum = 0.f;
#pragma unroll
    for (int m = 0; m < 49; m++) {
        float e = __expf(srow[m] - mx);
        srow[m] = e;
        sum += e;
    }
    float inv = 1.f / sum;

    float o[32];
#pragma unroll
    for (int d = 0; d < 32; d++) o[d] = 0.f;
#pragma unroll
    for (int m = 0; m < 49; m++) {
        const float* vr = &vs[m * 32];
        float pm = srow[m];
#pragma unroll
        for (int d = 0; d < 32; d++) o[d] += pm * vr[d];
    }
    if (active) {
        bf16* op = out + ((size_t)wl * 49 + l) * 384 + h * 32;
#pragma unroll
        for (int d = 0; d < 32; d++) op[d] = __float2bfloat16(o[d] * inv);
    }
}

// ---------------- host launch ----------------
extern "C" void kernel_launch(void* const* d_in, const int* in_sizes, int n_in,
                              void* d_out, int out_size, void* d_ws, size_t ws_size,
                              hipStream_t stream) {
    const float* x       = (const float*)d_in[0];
    const float* norm1_g = (const float*)d_in[1];
    const float* norm1_b = (const float*)d_in[2];
    const float* qkv_w   = (const float*)d_in[3];
    const float* qkv_b   = (const float*)d_in[4];
    const float* rpb     = (const float*)d_in[5];
    const float* proj_w  = (const float*)d_in[6];
    const float* proj_b  = (const float*)d_in[7];
    const float* norm2_g = (const float*)d_in[8];
    const float* norm2_b = (const float*)d_in[9];
    const float* fc1_w   = (const float*)d_in[10];
    const float* fc1_b   = (const float*)d_in[11];
    const float* fc2_w   = (const float*)d_in[12];
    const float* fc2_b   = (const float*)d_in[13];
    (void)in_sizes; (void)n_in; (void)out_size;

    int nc = (ws_size >= (size_t)199753728) ? 2 : 4;
    int rows = TOK / nc;               // 25088 or 12544
    int wins = rows / 49;              // 512 or 256
    size_t arena_sz = (size_t)rows * 1152 * 2 + (size_t)rows * 384 * 2;

    float* xres  = (float*)d_ws;                              // 77,070,336 B
    bf16* lnbuf  = (bf16*)((char*)d_ws + 77070336);           // 38,535,168 B
    char* arena  = (char*)d_ws + 115605504;                   // arena_sz B
    bf16* wT     = (bf16*)((char*)d_ws + 115605504 + arena_sz); // 7,077,888 B

    bf16* qkvbuf  = (bf16*)arena;
    bf16* attnbuf = (bf16*)(arena + (size_t)rows * 1152 * 2);
    bf16* fc1buf  = (bf16*)arena;     // rows*1536*2 <= rows*1152*2 + rows*384*2

    bf16* qkvT  = wT;                          // 2 x 1152*384
    bf16* projT = wT + 884736;                 // 2 x 384*384
    bf16* fc1T  = projT + 294912;              // 2 x 1536*384
    bf16* fc2T  = fc1T + 1179648;              // 2 x 384*1536

    for (int i = 0; i < 2; i++) {
        k_transpose<<<(384 * 1152 + 255) / 256, 256, 0, stream>>>(
            qkv_w + (size_t)i * 442368, qkvT + (size_t)i * 442368, 384, 1152);
        k_transpose<<<(384 * 384 + 255) / 256, 256, 0, stream>>>(
            proj_w + (size_t)i * 147456, projT + (size_t)i * 147456, 384, 384);
        k_transpose<<<(384 * 1536 + 255) / 256, 256, 0, stream>>>(
            fc1_w + (size_t)i * 589824, fc1T + (size_t)i * 589824, 384, 1536);
        k_transpose<<<(1536 * 384 + 255) / 256, 256, 0, stream>>>(
            fc2_w + (size_t)i * 589824, fc2T + (size_t)i * 589824, 1536, 384);
    }

    for (int i = 0; i < 2; i++) {
        int shift = (i == 0) ? 0 : 3;
        // block 0 reads the input x directly (xres not yet materialized);
        // proj's epilogue then writes xres = x + o, eliminating the k_cvt copy.
        const float* resid = (i == 0) ? x : xres;
        k_ln<<<TOK / 4, 256, 0, stream>>>(resid, norm1_g + i * 384, norm1_b + i * 384,
                                          lnbuf, shift, 1);
        for (int c = 0; c < nc; c++) {
            const bf16* Ac = lnbuf + (size_t)c * rows * 384;
            k_gemm<<<dim3(rows / 128, 9), 256, 0, stream>>>(
                Ac, qkvT + (size_t)i * 442368, qkv_b + i * 1152, 384, 1152,
                qkvbuf, nullptr, nullptr, nullptr, GM_QKV, 0, 0);
            k_attn<<<wins * 12 / 4, 256, 0, stream>>>(qkvbuf, rpb + i * 2028,
                                                      attnbuf, shift, c * wins);
            k_gemm<<<dim3(rows / 128, 3), 256, 0, stream>>>(
                attnbuf, projT + (size_t)i * 147456, proj_b + i * 384, 384, 384,
                nullptr, xres, nullptr, resid, GM_PROJ, shift, c * rows);
        }
        k_ln<<<TOK / 4, 256, 0, stream>>>(xres, norm2_g + i * 384, norm2_b + i * 384,
                                          lnbuf, 0, 0);
        for (int c = 0; c < nc; c++) {
            const bf16* Ac = lnbuf + (size_t)c * rows * 384;
            k_gemm<<<dim3(rows / 128, 12), 256, 0, stream>>>(
                Ac, fc1T + (size_t)i * 589824, fc1_b + i * 1536, 384, 1536,
                fc1buf, nullptr, nullptr, nullptr, GM_FC1, 0, 0);
            k_gemm<<<dim3(rows / 128, 3), 256, 0, stream>>>(
                fc1buf, fc2T + (size_t)i * 589824, fc2_b + i * 384, 1536, 384,
                nullptr, xres, (float*)d_out, nullptr,
                (i == 0) ? GM_FC2 : GM_FC2OUT, 0, c * rows);
        }
    }
}

// Round 5
// 1443.080 us; speedup vs baseline: 1.5391x; 1.0181x over previous
//
#include <hip/hip_runtime.h>
#include <hip/hip_bf16.h>
#include <math.h>

using bf16 = __hip_bfloat16;
typedef __bf16 bf16x8 __attribute__((ext_vector_type(8)));
typedef float f32x4 __attribute__((ext_vector_type(4)));

static constexpr int TOK = 16 * 56 * 56;   // 50176 tokens
static constexpr int CDIM = 384;
static constexpr float SCALE = 0.17677669529663687f; // 32^-0.5

// ---------------- weight transpose fp32 [K,N] -> bf16 [N,K] ----------------
__global__ void k_transpose(const float* __restrict__ in, bf16* __restrict__ out,
                            int K, int N) {
    int idx = blockIdx.x * 256 + threadIdx.x;
    if (idx >= K * N) return;
    int k = idx / N, n = idx - k * N;
    out[(size_t)n * K + k] = __float2bfloat16(in[idx]);
}

// ---------------- LayerNorm (+ optional roll + window partition) ----------------
__global__ __launch_bounds__(256) void k_ln(const float* __restrict__ src,
                                            const float* __restrict__ g,
                                            const float* __restrict__ bta,
                                            bf16* __restrict__ out,
                                            int shift, int windowed) {
    int wave = threadIdx.x >> 6, l = threadIdx.x & 63;
    int t = blockIdx.x * 4 + wave;
    int srow;
    if (windowed) {
        int wi = t / 49, n = t - wi * 49;
        int b_ = wi >> 6, w64 = wi & 63;
        int wy = w64 >> 3, wx = w64 & 7;
        int pin = n / 7, qin = n - pin * 7;
        int hs = wy * 7 + pin + shift; if (hs >= 56) hs -= 56;
        int ws2 = wx * 7 + qin + shift; if (ws2 >= 56) ws2 -= 56;
        srow = b_ * 3136 + hs * 56 + ws2;
    } else {
        srow = t;
    }
    const float* xr = src + (size_t)srow * CDIM;
    float v[6];
    float s = 0.f;
#pragma unroll
    for (int j = 0; j < 6; j++) { v[j] = xr[j * 64 + l]; s += v[j]; }
#pragma unroll
    for (int off = 32; off; off >>= 1) s += __shfl_xor(s, off, 64);
    float mean = s * (1.f / 384.f);
    float sq = 0.f;
#pragma unroll
    for (int j = 0; j < 6; j++) { float d = v[j] - mean; sq += d * d; }
#pragma unroll
    for (int off = 32; off; off >>= 1) sq += __shfl_xor(sq, off, 64);
    float rstd = rsqrtf(sq * (1.f / 384.f) + 1e-5f);
    bf16* op = out + (size_t)t * CDIM;
#pragma unroll
    for (int j = 0; j < 6; j++) {
        int c = j * 64 + l;
        float val = (v[j] - mean) * rstd * g[c] + bta[c];
        op[c] = __float2bfloat16(val);
    }
}

// -------- MFMA GEMM: 3-buffer counted-vmcnt pipeline + conflict-free LDS -----
#define GM_QKV    0
#define GM_PROJ   1
#define GM_FC1    2
#define GM_FC2    3
#define GM_FC2OUT 4

__device__ __forceinline__ void gld16(const void* g, void* l) {
    __builtin_amdgcn_global_load_lds(
        (const __attribute__((address_space(1))) void*)g,
        (__attribute__((address_space(3))) void*)l, 16, 0, 0);
}

__device__ __forceinline__ void store4bf(bf16* p, f32x4 v) {
    union { unsigned short us[4]; uint2 u2; } pk;
#pragma unroll
    for (int i = 0; i < 4; i++) {
        __hip_bfloat16 h = __float2bfloat16(v[i]);
        pk.us[i] = *reinterpret_cast<unsigned short*>(&h);
    }
    *reinterpret_cast<uint2*>(p) = pk.u2;
}

__global__ __launch_bounds__(256) void k_gemm(
    const bf16* __restrict__ A, const bf16* __restrict__ Bt,
    const float* __restrict__ bias, int K, int Nout,
    bf16* __restrict__ obf, float* __restrict__ xres, float* __restrict__ ofinal,
    const float* __restrict__ shortcut,
    int mode, int shift, int m_base) {
    __shared__ __align__(16) bf16 As[3][128 * 32];
    __shared__ __align__(16) bf16 Bs[3][128 * 32];
    int tid = threadIdx.x;
    int w = tid >> 6, l = tid & 63;

    // XCD-chunked, panel-major swizzle (bijective): all N-tiles of one A-panel
    // run consecutively on one XCD -> staging loads hit that XCD's L2
    // (verified: FETCH 80MB -> 25MB == ideal for FC1).
    int nx = gridDim.x, ny = gridDim.y;
    int nwg = nx * ny;
    int bid = blockIdx.y * nx + blockIdx.x;     // dispatch order (x fastest)
    int xcd = bid & 7, slot = bid >> 3;
    int qch = nwg >> 3, rch = nwg & 7;
    int wk = (xcd < rch ? xcd * (qch + 1) : rch * (qch + 1) + (xcd - rch) * qch)
             + slot;
    int bx = wk / ny, by = wk - bx * ny;
    int m0 = bx * 128, n0 = by * 128;

    int wm = (w >> 1) * 64, wn = (w & 1) * 64;

    f32x4 acc[4][4];
#pragma unroll
    for (int i = 0; i < 4; i++)
#pragma unroll
        for (int j = 0; j < 4; j++) acc[i][j] = f32x4{0.f, 0.f, 0.f, 0.f};

    // Staging: 512 slots of 16B per matrix; thread t handles slots t, t+256.
    // Bank-conflict fix (rule #21: swizzle source AND read, LDS dest linear):
    // LDS slot (row, c) receives global chunk c ^ ((row>>1)&3). The ds_read
    // XORs the same term back. Turns the 8-way row-alias conflict (64B row
    // stride, 128B bank period) into 2-way == free.
    int swzc = ((tid & 3) ^ ((tid >> 3) & 3)) * 8;   // same for slot t and t+256
    int ar0 = tid >> 2, ar1 = ar0 + 64;
    const bf16* Ag0 = A + (size_t)(m0 + ar0) * K + swzc;
    const bf16* Ag1 = A + (size_t)(m0 + ar1) * K + swzc;
    const bf16* Bg0 = Bt + (size_t)(n0 + ar0) * K + swzc;
    const bf16* Bg1 = Bt + (size_t)(n0 + ar1) * K + swzc;
    char* a0 = (char*)As + (size_t)(w * 64) * 16;    // wave's linear DMA dest
    char* b0 = (char*)Bs + (size_t)(w * 64) * 16;

    int q = l >> 4, r = l & 15;
    int qs = (q ^ ((r >> 1) & 3)) * 8;               // swizzled read column

    auto stage = [&](int buf, int kt) {
        int kk = kt * 32;
        char* ad = a0 + buf * 8192;
        char* bd = b0 + buf * 8192;
        gld16(Ag0 + kk, ad);
        gld16(Ag1 + kk, ad + 4096);
        gld16(Bg0 + kk, bd);
        gld16(Bg1 + kk, bd + 4096);
    };
    // mfma(bfr, af): C/D row dim = B-side; lane (q,r) holds output row
    // wm+mi*16+r, cols wn+ni*16+q*4..+3 -> vectorized epilogue.
    auto compute = [&](int buf) {
        const bf16* Ax = &As[0][0] + buf * 4096;
        const bf16* Bx = &Bs[0][0] + buf * 4096;
        bf16x8 af[4], bfr[4];
#pragma unroll
        for (int mi = 0; mi < 4; mi++)
            af[mi] = *(const bf16x8*)&Ax[(wm + mi * 16 + r) * 32 + qs];
#pragma unroll
        for (int ni = 0; ni < 4; ni++)
            bfr[ni] = *(const bf16x8*)&Bx[(wn + ni * 16 + r) * 32 + qs];
#pragma unroll
        for (int mi = 0; mi < 4; mi++)
#pragma unroll
            for (int ni = 0; ni < 4; ni++)
                acc[mi][ni] = __builtin_amdgcn_mfma_f32_16x16x32_bf16(
                    bfr[ni], af[mi], acc[mi][ni], 0, 0, 0);
    };

    // 3-deep circular pipeline, counted vmcnt (T4): tile t+2 is issued right
    // after the iter-t barrier and waited two compute-phases later -> ~2x
    // K-step of latency cover (>= HBM ~900cyc). vmcnt(4) leaves the next
    // tile's 4 loads in flight across the barrier. Reuse safety: stage(t+2)
    // overwrites buf(t-1); all reads of buf(t-1) completed before this
    // barrier (lgkmcnt before MFMA + barrier ordering).
    const int nk = K >> 5;                 // 12 or 48
    stage(0, 0);
    stage(1, 1);
    int cb = 0, nb = 2;
    for (int t = 0; t < nk - 2; ++t) {
        asm volatile("s_waitcnt vmcnt(4)" ::: "memory");
        __builtin_amdgcn_s_barrier();
        stage(nb, t + 2);
        compute(cb);
        cb = (cb == 2) ? 0 : cb + 1;
        nb = (nb == 2) ? 0 : nb + 1;
    }
    asm volatile("s_waitcnt vmcnt(4)" ::: "memory");
    __builtin_amdgcn_s_barrier();
    compute(cb);
    cb = (cb == 2) ? 0 : cb + 1;
    asm volatile("s_waitcnt vmcnt(0)" ::: "memory");
    __builtin_amdgcn_s_barrier();
    compute(cb);

    // epilogue: row = wm+mi*16+r (4 rows/thread), cols = wn+ni*16+q*4..+3
#pragma unroll
    for (int mi = 0; mi < 4; mi++) {
        int grow = m0 + wm + mi * 16 + r;       // chunk-local output row
        size_t rowbase;
        if (mode == GM_PROJ) {
            int growg = m_base + grow;
            int wi = growg / 49, n = growg - wi * 49;
            int b_ = wi >> 6, w64 = wi & 63;
            int wy = w64 >> 3, wx = w64 & 7;
            int pin = n / 7, qin = n - pin * 7;
            int hs = wy * 7 + pin + shift; if (hs >= 56) hs -= 56;
            int ws2 = wx * 7 + qin + shift; if (ws2 >= 56) ws2 -= 56;
            rowbase = ((size_t)b_ * 3136 + hs * 56 + ws2) * CDIM;
        } else if (mode == GM_QKV || mode == GM_FC1) {
            rowbase = (size_t)grow * Nout;
        } else {
            rowbase = (size_t)(m_base + grow) * CDIM;
        }
#pragma unroll
        for (int ni = 0; ni < 4; ni++) {
            int gc0 = n0 + wn + ni * 16 + q * 4;
            const f32x4 bv = *(const f32x4*)&bias[gc0];
            f32x4 vv;
#pragma unroll
            for (int rr = 0; rr < 4; rr++) vv[rr] = acc[mi][ni][rr] + bv[rr];
            if (mode == GM_QKV) {
                store4bf(obf + rowbase + gc0, vv);
            } else if (mode == GM_FC1) {
#pragma unroll
                for (int rr = 0; rr < 4; rr++) {
                    float v = vv[rr];
                    // tanh-form GELU: |err| < 4e-4, below bf16 rounding.
                    float u = v * (0.7978845608028654f
                                   + 0.0356774081363001f * v * v);
                    float t = 1.f - 2.f / (1.f + __expf(2.f * u));
                    vv[rr] = 0.5f * v * (1.f + t);
                }
                store4bf(obf + rowbase + gc0, vv);
            } else if (mode == GM_PROJ) {
                const f32x4 sc = *(const f32x4*)(shortcut + rowbase + gc0);
#pragma unroll
                for (int rr = 0; rr < 4; rr++) vv[rr] += sc[rr];
                *(f32x4*)(xres + rowbase + gc0) = vv;
            } else {
                const f32x4 old = *(const f32x4*)(xres + rowbase + gc0);
#pragma unroll
                for (int rr = 0; rr < 4; rr++) vv[rr] += old[rr];
                if (mode == GM_FC2) *(f32x4*)(xres + rowbase + gc0) = vv;
                else *(f32x4*)(ofinal + rowbase + gc0) = vv;  // fp32 final out
            }
        }
    }
}

// ---------------- windowed attention v2: wave per (window,head), 4 waves/block ----
__device__ __forceinline__ int regionof(int p) {
    return (p < 49) ? 0 : (p < 53 ? 1 : 2);
}

__global__ __launch_bounds__(256) void k_attn(const bf16* __restrict__ qkv,
                                              const float* __restrict__ rpb,
                                              bf16* __restrict__ out, int shift,
                                              int wi0) {
    __shared__ float kv[4][2][49 * 32];   // [wave][k/v] = 50176 B total
    int wave = threadIdx.x >> 6, l = threadIdx.x & 63;
    int p = blockIdx.x * 4 + wave;        // chunk-local (window,head) pair
    int wl = p / 12, h = p - wl * 12;
    int wig = wi0 + wl;
    float* ks = kv[wave][0];
    float* vs = kv[wave][1];

    const bf16* base = qkv + (size_t)wl * 49 * 1152 + h * 32;
#pragma unroll
    for (int it = 0; it < 25; it++) {
        int idx = l + it * 64;
        if (idx < 1568) {
            int n = idx >> 5, d = idx & 31;
            size_t ro = (size_t)n * 1152 + d;
            ks[idx] = __bfloat162float(base[ro + 384]);
            vs[idx] = __bfloat162float(base[ro + 768]);
        }
    }
    int active = (l < 49);
    int le = active ? l : 0;
    float qreg[32];
    const bf16* qrow = base + (size_t)le * 1152;
#pragma unroll
    for (int d = 0; d < 32; d++) qreg[d] = __bfloat162float(qrow[d]) * SCALE;
    __syncthreads();

    int pin = le / 7, qin = le - (le / 7) * 7;
    int w64 = wig & 63;
    int py = (w64 >> 3) * 7, px = (w64 & 7) * 7;
    int regq = regionof(py + pin) * 3 + regionof(px + qin);

    float srow[49];
    float mx = -1e30f;
#pragma unroll
    for (int m = 0; m < 49; m++) {
        const float* kr = &ks[m * 32];
        float s = 0.f;
#pragma unroll
        for (int d = 0; d < 32; d++) s += qreg[d] * kr[d];
        const int mp = m / 7, mq = m - (m / 7) * 7;
        s += rpb[((pin - mp + 6) * 13 + (qin - mq + 6)) * 12 + h];
        if (shift > 0) {
            int regm = regionof(py + mp) * 3 + regionof(px + mq);
            if (regm != regq) s -= 100.f;
        }
        srow[m] = s;
        mx = fmaxf(mx, s);
    }
    float sum = 0.f;
#pragma unroll
    for (int m = 0; m < 49; m++) {
        float e = __expf(srow[m] - mx);
        srow[m] = e;
        sum += e;
    }
    float inv = 1.f / sum;

    float o[32];
#pragma unroll
    for (int d = 0; d < 32; d++) o[d] = 0.f;
#pragma unroll
    for (int m = 0; m < 49; m++) {
        const float* vr = &vs[m * 32];
        float pm = srow[m];
#pragma unroll
        for (int d = 0; d < 32; d++) o[d] += pm * vr[d];
    }
    if (active) {
        bf16* op = out + ((size_t)wl * 49 + l) * 384 + h * 32;
#pragma unroll
        for (int d = 0; d < 32; d++) op[d] = __float2bfloat16(o[d] * inv);
    }
}

// ---------------- host launch ----------------
extern "C" void kernel_launch(void* const* d_in, const int* in_sizes, int n_in,
                              void* d_out, int out_size, void* d_ws, size_t ws_size,
                              hipStream_t stream) {
    const float* x       = (const float*)d_in[0];
    const float* norm1_g = (const float*)d_in[1];
    const float* norm1_b = (const float*)d_in[2];
    const float* qkv_w   = (const float*)d_in[3];
    const float* qkv_b   = (const float*)d_in[4];
    const float* rpb     = (const float*)d_in[5];
    const float* proj_w  = (const float*)d_in[6];
    const float* proj_b  = (const float*)d_in[7];
    const float* norm2_g = (const float*)d_in[8];
    const float* norm2_b = (const float*)d_in[9];
    const float* fc1_w   = (const float*)d_in[10];
    const float* fc1_b   = (const float*)d_in[11];
    const float* fc2_w   = (const float*)d_in[12];
    const float* fc2_b   = (const float*)d_in[13];
    (void)in_sizes; (void)n_in; (void)out_size;

    int nc = (ws_size >= (size_t)199753728) ? 2 : 4;
    int rows = TOK / nc;               // 25088 or 12544
    int wins = rows / 49;              // 512 or 256
    size_t arena_sz = (size_t)rows * 1152 * 2 + (size_t)rows * 384 * 2;

    float* xres  = (float*)d_ws;                              // 77,070,336 B
    bf16* lnbuf  = (bf16*)((char*)d_ws + 77070336);           // 38,535,168 B
    char* arena  = (char*)d_ws + 115605504;                   // arena_sz B
    bf16* wT     = (bf16*)((char*)d_ws + 115605504 + arena_sz); // 7,077,888 B

    bf16* qkvbuf  = (bf16*)arena;
    bf16* attnbuf = (bf16*)(arena + (size_t)rows * 1152 * 2);
    bf16* fc1buf  = (bf16*)arena;     // rows*1536*2 <= rows*1152*2 + rows*384*2

    bf16* qkvT  = wT;                          // 2 x 1152*384
    bf16* projT = wT + 884736;                 // 2 x 384*384
    bf16* fc1T  = projT + 294912;              // 2 x 1536*384
    bf16* fc2T  = fc1T + 1179648;              // 2 x 384*1536

    for (int i = 0; i < 2; i++) {
        k_transpose<<<(384 * 1152 + 255) / 256, 256, 0, stream>>>(
            qkv_w + (size_t)i * 442368, qkvT + (size_t)i * 442368, 384, 1152);
        k_transpose<<<(384 * 384 + 255) / 256, 256, 0, stream>>>(
            proj_w + (size_t)i * 147456, projT + (size_t)i * 147456, 384, 384);
        k_transpose<<<(384 * 1536 + 255) / 256, 256, 0, stream>>>(
            fc1_w + (size_t)i * 589824, fc1T + (size_t)i * 589824, 384, 1536);
        k_transpose<<<(1536 * 384 + 255) / 256, 256, 0, stream>>>(
            fc2_w + (size_t)i * 589824, fc2T + (size_t)i * 589824, 1536, 384);
    }

    for (int i = 0; i < 2; i++) {
        int shift = (i == 0) ? 0 : 3;
        // block 0 reads the input x directly (xres not yet materialized);
        // proj's epilogue then writes xres = x + o, eliminating the k_cvt copy.
        const float* resid = (i == 0) ? x : xres;
        k_ln<<<TOK / 4, 256, 0, stream>>>(resid, norm1_g + i * 384, norm1_b + i * 384,
                                          lnbuf, shift, 1);
        for (int c = 0; c < nc; c++) {
            const bf16* Ac = lnbuf + (size_t)c * rows * 384;
            k_gemm<<<dim3(rows / 128, 9), 256, 0, stream>>>(
                Ac, qkvT + (size_t)i * 442368, qkv_b + i * 1152, 384, 1152,
                qkvbuf, nullptr, nullptr, nullptr, GM_QKV, 0, 0);
            k_attn<<<wins * 12 / 4, 256, 0, stream>>>(qkvbuf, rpb + i * 2028,
                                                      attnbuf, shift, c * wins);
            k_gemm<<<dim3(rows / 128, 3), 256, 0, stream>>>(
                attnbuf, projT + (size_t)i * 147456, proj_b + i * 384, 384, 384,
                nullptr, xres, nullptr, resid, GM_PROJ, shift, c * rows);
        }
        k_ln<<<TOK / 4, 256, 0, stream>>>(xres, norm2_g + i * 384, norm2_b + i * 384,
                                          lnbuf, 0, 0);
        for (int c = 0; c < nc; c++) {
            const bf16* Ac = lnbuf + (size_t)c * rows * 384;
            k_gemm<<<dim3(rows / 128, 12), 256, 0, stream>>>(
                Ac, fc1T + (size_t)i * 589824, fc1_b + i * 1536, 384, 1536,
                fc1buf, nullptr, nullptr, nullptr, GM_FC1, 0, 0);
            k_gemm<<<dim3(rows / 128, 3), 256, 0, stream>>>(
                fc1buf, fc2T + (size_t)i * 589824, fc2_b + i * 384, 1536, 384,
                nullptr, xres, (float*)d_out, nullptr,
                (i == 0) ? GM_FC2 : GM_FC2OUT, 0, c * rows);
        }
    }
}

// Round 7
// 1380.614 us; speedup vs baseline: 1.6087x; 1.0452x over previous
//
#include <hip/hip_runtime.h>
#include <hip/hip_bf16.h>
#include <math.h>

using bf16 = __hip_bfloat16;
typedef __bf16 bf16x8 __attribute__((ext_vector_type(8)));
typedef float f32x4 __attribute__((ext_vector_type(4)));

static constexpr int TOK = 16 * 56 * 56;   // 50176 tokens
static constexpr int CDIM = 384;
static constexpr float SCALE = 0.17677669529663687f; // 32^-0.5

// ---------------- weight transpose fp32 [K,N] -> bf16 [N,K] ----------------
__global__ void k_transpose(const float* __restrict__ in, bf16* __restrict__ out,
                            int K, int N) {
    int idx = blockIdx.x * 256 + threadIdx.x;
    if (idx >= K * N) return;
    int k = idx / N, n = idx - k * N;
    out[(size_t)n * K + k] = __float2bfloat16(in[idx]);
}

// ---------------- LayerNorm (+ optional roll + window partition) ----------------
__global__ __launch_bounds__(256) void k_ln(const float* __restrict__ src,
                                            const float* __restrict__ g,
                                            const float* __restrict__ bta,
                                            bf16* __restrict__ out,
                                            int shift, int windowed) {
    int wave = threadIdx.x >> 6, l = threadIdx.x & 63;
    int t = blockIdx.x * 4 + wave;
    int srow;
    if (windowed) {
        int wi = t / 49, n = t - wi * 49;
        int b_ = wi >> 6, w64 = wi & 63;
        int wy = w64 >> 3, wx = w64 & 7;
        int pin = n / 7, qin = n - pin * 7;
        int hs = wy * 7 + pin + shift; if (hs >= 56) hs -= 56;
        int ws2 = wx * 7 + qin + shift; if (ws2 >= 56) ws2 -= 56;
        srow = b_ * 3136 + hs * 56 + ws2;
    } else {
        srow = t;
    }
    const float* xr = src + (size_t)srow * CDIM;
    float v[6];
    float s = 0.f;
#pragma unroll
    for (int j = 0; j < 6; j++) { v[j] = xr[j * 64 + l]; s += v[j]; }
#pragma unroll
    for (int off = 32; off; off >>= 1) s += __shfl_xor(s, off, 64);
    float mean = s * (1.f / 384.f);
    float sq = 0.f;
#pragma unroll
    for (int j = 0; j < 6; j++) { float d = v[j] - mean; sq += d * d; }
#pragma unroll
    for (int off = 32; off; off >>= 1) sq += __shfl_xor(sq, off, 64);
    float rstd = rsqrtf(sq * (1.f / 384.f) + 1e-5f);
    bf16* op = out + (size_t)t * CDIM;
#pragma unroll
    for (int j = 0; j < 6; j++) {
        int c = j * 64 + l;
        float val = (v[j] - mean) * rstd * g[c] + bta[c];
        op[c] = __float2bfloat16(val);
    }
}

// -------- MFMA GEMM: 128x64 tile, halved acc state -> higher residency -------
#define GM_QKV    0
#define GM_PROJ   1
#define GM_FC1    2
#define GM_FC2    3
#define GM_FC2OUT 4

__device__ __forceinline__ void gld16(const void* g, void* l) {
    __builtin_amdgcn_global_load_lds(
        (const __attribute__((address_space(1))) void*)g,
        (__attribute__((address_space(3))) void*)l, 16, 0, 0);
}

__device__ __forceinline__ void store4bf(bf16* p, f32x4 v) {
    union { unsigned short us[4]; uint2 u2; } pk;
#pragma unroll
    for (int i = 0; i < 4; i++) {
        __hip_bfloat16 h = __float2bfloat16(v[i]);
        pk.us[i] = *reinterpret_cast<unsigned short*>(&h);
    }
    *reinterpret_cast<uint2*>(p) = pk.u2;
}

__global__ __launch_bounds__(256) void k_gemm(
    const bf16* __restrict__ A, const bf16* __restrict__ Bt,
    const float* __restrict__ bias, int K, int Nout,
    bf16* __restrict__ obf, float* __restrict__ xres, float* __restrict__ ofinal,
    const float* __restrict__ shortcut,
    int mode, int shift, int m_base) {
    // Tile 128(M) x 64(N), BK=32, 4 waves each owning a 64x32 sub-tile.
    // acc/thread = 8 f32x4 (32 regs, was 64) -> ~4 blocks/CU resident
    // (occupancy was 13%: per-thread state capped residency at 1-2 blocks
    // and barrier-locked waves had no TLP to hide ds_read/MFMA latency).
    __shared__ __align__(16) bf16 As[3][128 * 32];   // 3 x 8KB
    __shared__ __align__(16) bf16 Bs[3][64 * 32];    // 3 x 4KB
    int tid = threadIdx.x;
    int w = tid >> 6, l = tid & 63;

    // XCD-chunked, panel-major swizzle (bijective): all N-tiles of one A-panel
    // run consecutively on one XCD -> staging re-reads hit that XCD's L2.
    int nx = gridDim.x, ny = gridDim.y;
    int nwg = nx * ny;
    int bid = blockIdx.y * nx + blockIdx.x;     // dispatch order (x fastest)
    int xcd = bid & 7, slot = bid >> 3;
    int qch = nwg >> 3, rch = nwg & 7;
    int wk = (xcd < rch ? xcd * (qch + 1) : rch * (qch + 1) + (xcd - rch) * qch)
             + slot;
    int bx = wk / ny, by = wk - bx * ny;
    int m0 = bx * 128, n0 = by * 64;

    int wm = (w >> 1) * 64, wn = (w & 1) * 32;

    f32x4 acc[4][2];
#pragma unroll
    for (int i = 0; i < 4; i++)
#pragma unroll
        for (int j = 0; j < 2; j++) acc[i][j] = f32x4{0.f, 0.f, 0.f, 0.f};

    // Staging: A = 512 slots of 16B (thread t -> slots t, t+256);
    //          B = 256 slots (thread t -> slot t). 3 loads/thread/K-step.
    // Bank-conflict swizzle (verified: 3.6M -> 0): LDS slot (row,c) receives
    // global chunk c ^ ((row>>1)&3); ds_read XORs the same term back.
    int swzc = ((tid & 3) ^ ((tid >> 3) & 3)) * 8;   // valid for t and t+256
    int ar0 = tid >> 2, ar1 = ar0 + 64;
    const bf16* Ag0 = A + (size_t)(m0 + ar0) * K + swzc;
    const bf16* Ag1 = A + (size_t)(m0 + ar1) * K + swzc;
    const bf16* Bg0 = Bt + (size_t)(n0 + ar0) * K + swzc;
    char* a0 = (char*)As + (size_t)(w * 64) * 16;    // wave's linear DMA dest
    char* b0 = (char*)Bs + (size_t)(w * 64) * 16;

    int q = l >> 4, r = l & 15;
    int qs = (q ^ ((r >> 1) & 3)) * 8;               // swizzled read column

    auto stage = [&](int buf, int kt) {
        int kk = kt * 32;
        char* ad = a0 + buf * 8192;
        char* bd = b0 + buf * 4096;
        gld16(Ag0 + kk, ad);
        gld16(Ag1 + kk, ad + 4096);
        gld16(Bg0 + kk, bd);
    };
    // mfma(bfr, af): C/D row dim = A-side row wm+mi*16+r,
    // cols = wn+ni*16+q*4..+3 -> vectorized epilogue.
    auto compute = [&](int buf) {
        const bf16* Ax = &As[0][0] + buf * 4096;
        const bf16* Bx = &Bs[0][0] + buf * 2048;
        bf16x8 af[4], bfr[2];
#pragma unroll
        for (int mi = 0; mi < 4; mi++)
            af[mi] = *(const bf16x8*)&Ax[(wm + mi * 16 + r) * 32 + qs];
#pragma unroll
        for (int ni = 0; ni < 2; ni++)
            bfr[ni] = *(const bf16x8*)&Bx[(wn + ni * 16 + r) * 32 + qs];
#pragma unroll
        for (int mi = 0; mi < 4; mi++)
#pragma unroll
            for (int ni = 0; ni < 2; ni++)
                acc[mi][ni] = __builtin_amdgcn_mfma_f32_16x16x32_bf16(
                    bfr[ni], af[mi], acc[mi][ni], 0, 0, 0);
    };

    // 3-deep circular pipeline, counted vmcnt: tile t+2 issued right after the
    // iter-t barrier, waited two compute-phases later. 3 loads/thread/stage ->
    // vmcnt(3) leaves the newest tile in flight across the barrier.
    const int nk = K >> 5;                 // 12 or 48
    stage(0, 0);
    stage(1, 1);
    int cb = 0, nb = 2;
    for (int t = 0; t < nk - 2; ++t) {
        asm volatile("s_waitcnt vmcnt(3)" ::: "memory");
        __builtin_amdgcn_s_barrier();
        stage(nb, t + 2);
        compute(cb);
        cb = (cb == 2) ? 0 : cb + 1;
        nb = (nb == 2) ? 0 : nb + 1;
    }
    asm volatile("s_waitcnt vmcnt(3)" ::: "memory");
    __builtin_amdgcn_s_barrier();
    compute(cb);
    cb = (cb == 2) ? 0 : cb + 1;
    asm volatile("s_waitcnt vmcnt(0)" ::: "memory");
    __builtin_amdgcn_s_barrier();
    compute(cb);

    // epilogue: row = wm+mi*16+r (4 rows/thread), cols = wn+ni*16+q*4..+3
#pragma unroll
    for (int mi = 0; mi < 4; mi++) {
        int grow = m0 + wm + mi * 16 + r;       // chunk-local output row
        size_t rowbase;
        if (mode == GM_PROJ) {
            int growg = m_base + grow;
            int wi = growg / 49, n = growg - wi * 49;
            int b_ = wi >> 6, w64 = wi & 63;
            int wy = w64 >> 3, wx = w64 & 7;
            int pin = n / 7, qin = n - pin * 7;
            int hs = wy * 7 + pin + shift; if (hs >= 56) hs -= 56;
            int ws2 = wx * 7 + qin + shift; if (ws2 >= 56) ws2 -= 56;
            rowbase = ((size_t)b_ * 3136 + hs * 56 + ws2) * CDIM;
        } else if (mode == GM_QKV || mode == GM_FC1) {
            rowbase = (size_t)grow * Nout;
        } else {
            rowbase = (size_t)(m_base + grow) * CDIM;
        }
#pragma unroll
        for (int ni = 0; ni < 2; ni++) {
            int gc0 = n0 + wn + ni * 16 + q * 4;
            const f32x4 bv = *(const f32x4*)&bias[gc0];
            f32x4 vv;
#pragma unroll
            for (int rr = 0; rr < 4; rr++) vv[rr] = acc[mi][ni][rr] + bv[rr];
            if (mode == GM_QKV) {
                store4bf(obf + rowbase + gc0, vv);
            } else if (mode == GM_FC1) {
#pragma unroll
                for (int rr = 0; rr < 4; rr++) {
                    float v = vv[rr];
                    // tanh-form GELU: |err| < 4e-4, below bf16 rounding.
                    float u = v * (0.7978845608028654f
                                   + 0.0356774081363001f * v * v);
                    float t = 1.f - 2.f / (1.f + __expf(2.f * u));
                    vv[rr] = 0.5f * v * (1.f + t);
                }
                store4bf(obf + rowbase + gc0, vv);
            } else if (mode == GM_PROJ) {
                const f32x4 sc = *(const f32x4*)(shortcut + rowbase + gc0);
#pragma unroll
                for (int rr = 0; rr < 4; rr++) vv[rr] += sc[rr];
                *(f32x4*)(xres + rowbase + gc0) = vv;
            } else {
                const f32x4 old = *(const f32x4*)(xres + rowbase + gc0);
#pragma unroll
                for (int rr = 0; rr < 4; rr++) vv[rr] += old[rr];
                if (mode == GM_FC2) *(f32x4*)(xres + rowbase + gc0) = vv;
                else *(f32x4*)(ofinal + rowbase + gc0) = vv;  // fp32 final out
            }
        }
    }
}

// ---------------- windowed attention v2: wave per (window,head), 4 waves/block ----
__device__ __forceinline__ int regionof(int p) {
    return (p < 49) ? 0 : (p < 53 ? 1 : 2);
}

__global__ __launch_bounds__(256) void k_attn(const bf16* __restrict__ qkv,
                                              const float* __restrict__ rpb,
                                              bf16* __restrict__ out, int shift,
                                              int wi0) {
    __shared__ float kv[4][2][49 * 32];   // [wave][k/v] = 50176 B total
    int wave = threadIdx.x >> 6, l = threadIdx.x & 63;
    int p = blockIdx.x * 4 + wave;        // chunk-local (window,head) pair
    int wl = p / 12, h = p - wl * 12;
    int wig = wi0 + wl;
    float* ks = kv[wave][0];
    float* vs = kv[wave][1];

    const bf16* base = qkv + (size_t)wl * 49 * 1152 + h * 32;
#pragma unroll
    for (int it = 0; it < 25; it++) {
        int idx = l + it * 64;
        if (idx < 1568) {
            int n = idx >> 5, d = idx & 31;
            size_t ro = (size_t)n * 1152 + d;
            ks[idx] = __bfloat162float(base[ro + 384]);
            vs[idx] = __bfloat162float(base[ro + 768]);
        }
    }
    int active = (l < 49);
    int le = active ? l : 0;
    float qreg[32];
    const bf16* qrow = base + (size_t)le * 1152;
#pragma unroll
    for (int d = 0; d < 32; d++) qreg[d] = __bfloat162float(qrow[d]) * SCALE;
    __syncthreads();

    int pin = le / 7, qin = le - (le / 7) * 7;
    int w64 = wig & 63;
    int py = (w64 >> 3) * 7, px = (w64 & 7) * 7;
    int regq = regionof(py + pin) * 3 + regionof(px + qin);

    float srow[49];
    float mx = -1e30f;
#pragma unroll
    for (int m = 0; m < 49; m++) {
        const float* kr = &ks[m * 32];
        float s = 0.f;
#pragma unroll
        for (int d = 0; d < 32; d++) s += qreg[d] * kr[d];
        const int mp = m / 7, mq = m - (m / 7) * 7;
        s += rpb[((pin - mp + 6) * 13 + (qin - mq + 6)) * 12 + h];
        if (shift > 0) {
            int regm = regionof(py + mp) * 3 + regionof(px + mq);
            if (regm != regq) s -= 100.f;
        }
        srow[m] = s;
        mx = fmaxf(mx, s);
    }
    float sum = 0.f;
#pragma unroll
    for (int m = 0; m < 49; m++) {
        float e = __expf(srow[m] - mx);
        srow[m] = e;
        sum += e;
    }
    float inv = 1.f / sum;

    float o[32];
#pragma unroll
    for (int d = 0; d < 32; d++) o[d] = 0.f;
#pragma unroll
    for (int m = 0; m < 49; m++) {
        const float* vr = &vs[m * 32];
        float pm = srow[m];
#pragma unroll
        for (int d = 0; d < 32; d++) o[d] += pm * vr[d];
    }
    if (active) {
        bf16* op = out + ((size_t)wl * 49 + l) * 384 + h * 32;
#pragma unroll
        for (int d = 0; d < 32; d++) op[d] = __float2bfloat16(o[d] * inv);
    }
}

// ---------------- host launch ----------------
extern "C" void kernel_launch(void* const* d_in, const int* in_sizes, int n_in,
                              void* d_out, int out_size, void* d_ws, size_t ws_size,
                              hipStream_t stream) {
    const float* x       = (const float*)d_in[0];
    const float* norm1_g = (const float*)d_in[1];
    const float* norm1_b = (const float*)d_in[2];
    const float* qkv_w   = (const float*)d_in[3];
    const float* qkv_b   = (const float*)d_in[4];
    const float* rpb     = (const float*)d_in[5];
    const float* proj_w  = (const float*)d_in[6];
    const float* proj_b  = (const float*)d_in[7];
    const float* norm2_g = (const float*)d_in[8];
    const float* norm2_b = (const float*)d_in[9];
    const float* fc1_w   = (const float*)d_in[10];
    const float* fc1_b   = (const float*)d_in[11];
    const float* fc2_w   = (const float*)d_in[12];
    const float* fc2_b   = (const float*)d_in[13];
    (void)in_sizes; (void)n_in; (void)out_size;

    int nc = (ws_size >= (size_t)199753728) ? 2 : 4;
    int rows = TOK / nc;               // 25088 or 12544
    int wins = rows / 49;              // 512 or 256
    size_t arena_sz = (size_t)rows * 1152 * 2 + (size_t)rows * 384 * 2;

    float* xres  = (float*)d_ws;                              // 77,070,336 B
    bf16* lnbuf  = (bf16*)((char*)d_ws + 77070336);           // 38,535,168 B
    char* arena  = (char*)d_ws + 115605504;                   // arena_sz B
    bf16* wT     = (bf16*)((char*)d_ws + 115605504 + arena_sz); // 7,077,888 B

    bf16* qkvbuf  = (bf16*)arena;
    bf16* attnbuf = (bf16*)(arena + (size_t)rows * 1152 * 2);
    bf16* fc1buf  = (bf16*)arena;     // rows*1536*2 <= rows*1152*2 + rows*384*2

    bf16* qkvT  = wT;                          // 2 x 1152*384
    bf16* projT = wT + 884736;                 // 2 x 384*384
    bf16* fc1T  = projT + 294912;              // 2 x 1536*384
    bf16* fc2T  = fc1T + 1179648;              // 2 x 384*1536

    for (int i = 0; i < 2; i++) {
        k_transpose<<<(384 * 1152 + 255) / 256, 256, 0, stream>>>(
            qkv_w + (size_t)i * 442368, qkvT + (size_t)i * 442368, 384, 1152);
        k_transpose<<<(384 * 384 + 255) / 256, 256, 0, stream>>>(
            proj_w + (size_t)i * 147456, projT + (size_t)i * 147456, 384, 384);
        k_transpose<<<(384 * 1536 + 255) / 256, 256, 0, stream>>>(
            fc1_w + (size_t)i * 589824, fc1T + (size_t)i * 589824, 384, 1536);
        k_transpose<<<(1536 * 384 + 255) / 256, 256, 0, stream>>>(
            fc2_w + (size_t)i * 589824, fc2T + (size_t)i * 589824, 1536, 384);
    }

    for (int i = 0; i < 2; i++) {
        int shift = (i == 0) ? 0 : 3;
        // block 0 reads the input x directly (xres not yet materialized);
        // proj's epilogue then writes xres = x + o, eliminating the k_cvt copy.
        const float* resid = (i == 0) ? x : xres;
        k_ln<<<TOK / 4, 256, 0, stream>>>(resid, norm1_g + i * 384, norm1_b + i * 384,
                                          lnbuf, shift, 1);
        for (int c = 0; c < nc; c++) {
            const bf16* Ac = lnbuf + (size_t)c * rows * 384;
            k_gemm<<<dim3(rows / 128, 18), 256, 0, stream>>>(
                Ac, qkvT + (size_t)i * 442368, qkv_b + i * 1152, 384, 1152,
                qkvbuf, nullptr, nullptr, nullptr, GM_QKV, 0, 0);
            k_attn<<<wins * 12 / 4, 256, 0, stream>>>(qkvbuf, rpb + i * 2028,
                                                      attnbuf, shift, c * wins);
            k_gemm<<<dim3(rows / 128, 6), 256, 0, stream>>>(
                attnbuf, projT + (size_t)i * 147456, proj_b + i * 384, 384, 384,
                nullptr, xres, nullptr, resid, GM_PROJ, shift, c * rows);
        }
        k_ln<<<TOK / 4, 256, 0, stream>>>(xres, norm2_g + i * 384, norm2_b + i * 384,
                                          lnbuf, 0, 0);
        for (int c = 0; c < nc; c++) {
            const bf16* Ac = lnbuf + (size_t)c * rows * 384;
            k_gemm<<<dim3(rows / 128, 24), 256, 0, stream>>>(
                Ac, fc1T + (size_t)i * 589824, fc1_b + i * 1536, 384, 1536,
                fc1buf, nullptr, nullptr, nullptr, GM_FC1, 0, 0);
            k_gemm<<<dim3(rows / 128, 6), 256, 0, stream>>>(
                fc1buf, fc2T + (size_t)i * 589824, fc2_b + i * 384, 1536, 384,
                nullptr, xres, (float*)d_out, nullptr,
                (i == 0) ? GM_FC2 : GM_FC2OUT, 0, c * rows);
        }
    }
}

// Round 8
// 1234.655 us; speedup vs baseline: 1.7989x; 1.1182x over previous
//
#include <hip/hip_runtime.h>
#include <hip/hip_bf16.h>
#include <math.h>

using bf16 = __hip_bfloat16;
typedef __bf16 bf16x8 __attribute__((ext_vector_type(8)));
typedef float f32x4 __attribute__((ext_vector_type(4)));

static constexpr int TOK = 16 * 56 * 56;   // 50176 tokens
static constexpr int CDIM = 384;
static constexpr float SCALE = 0.17677669529663687f; // 32^-0.5

// ---------------- weight transpose fp32 [K,N] -> bf16 [N,K] ----------------
__global__ void k_transpose(const float* __restrict__ in, bf16* __restrict__ out,
                            int K, int N) {
    int idx = blockIdx.x * 256 + threadIdx.x;
    if (idx >= K * N) return;
    int k = idx / N, n = idx - k * N;
    out[(size_t)n * K + k] = __float2bfloat16(in[idx]);
}

// ---------------- LayerNorm (+ optional roll + window partition) ----------------
__global__ __launch_bounds__(256) void k_ln(const float* __restrict__ src,
                                            const float* __restrict__ g,
                                            const float* __restrict__ bta,
                                            bf16* __restrict__ out,
                                            int shift, int windowed) {
    int wave = threadIdx.x >> 6, l = threadIdx.x & 63;
    int t = blockIdx.x * 4 + wave;
    int srow;
    if (windowed) {
        int wi = t / 49, n = t - wi * 49;
        int b_ = wi >> 6, w64 = wi & 63;
        int wy = w64 >> 3, wx = w64 & 7;
        int pin = n / 7, qin = n - pin * 7;
        int hs = wy * 7 + pin + shift; if (hs >= 56) hs -= 56;
        int ws2 = wx * 7 + qin + shift; if (ws2 >= 56) ws2 -= 56;
        srow = b_ * 3136 + hs * 56 + ws2;
    } else {
        srow = t;
    }
    const float* xr = src + (size_t)srow * CDIM;
    float v[6];
    float s = 0.f;
#pragma unroll
    for (int j = 0; j < 6; j++) { v[j] = xr[j * 64 + l]; s += v[j]; }
#pragma unroll
    for (int off = 32; off; off >>= 1) s += __shfl_xor(s, off, 64);
    float mean = s * (1.f / 384.f);
    float sq = 0.f;
#pragma unroll
    for (int j = 0; j < 6; j++) { float d = v[j] - mean; sq += d * d; }
#pragma unroll
    for (int off = 32; off; off >>= 1) sq += __shfl_xor(sq, off, 64);
    float rstd = rsqrtf(sq * (1.f / 384.f) + 1e-5f);
    bf16* op = out + (size_t)t * CDIM;
#pragma unroll
    for (int j = 0; j < 6; j++) {
        int c = j * 64 + l;
        float val = (v[j] - mean) * rstd * g[c] + bta[c];
        op[c] = __float2bfloat16(val);
    }
}

// ---- MFMA GEMM: 256x128 tile, 8 waves of 64x64 -> 1.5x FLOP per LDS byte ----
// LDS-pipe accounting (r7 was ~85% LDS saturated): reads/FLOP halve when the
// wave tile grows 64x32 -> 64x64 (each LDS byte feeds 2 MFMA column-frags).
#define GM_QKV    0
#define GM_PROJ   1
#define GM_FC1    2
#define GM_FC2    3
#define GM_FC2OUT 4

__device__ __forceinline__ void gld16(const void* g, void* l) {
    __builtin_amdgcn_global_load_lds(
        (const __attribute__((address_space(1))) void*)g,
        (__attribute__((address_space(3))) void*)l, 16, 0, 0);
}

__device__ __forceinline__ void store4bf(bf16* p, f32x4 v) {
    union { unsigned short us[4]; uint2 u2; } pk;
#pragma unroll
    for (int i = 0; i < 4; i++) {
        __hip_bfloat16 h = __float2bfloat16(v[i]);
        pk.us[i] = *reinterpret_cast<unsigned short*>(&h);
    }
    *reinterpret_cast<uint2*>(p) = pk.u2;
}

__global__ __launch_bounds__(512) void k_gemm(
    const bf16* __restrict__ A, const bf16* __restrict__ Bt,
    const float* __restrict__ bias, int K, int Nout,
    bf16* __restrict__ obf, float* __restrict__ xres, float* __restrict__ ofinal,
    const float* __restrict__ shortcut,
    int mode, int shift, int m_base) {
    // 256(M) x 128(N) tile, BK=32, 8 waves in a 4(M) x 2(N) grid, each wave
    // owns 64x64: acc = 16 f32x4. LDS 3-buf: A 3x16KB + B 3x8KB = 72 KB.
    __shared__ __align__(16) bf16 As[3][256 * 32];
    __shared__ __align__(16) bf16 Bs[3][128 * 32];
    int tid = threadIdx.x;
    int w = tid >> 6, l = tid & 63;

    // XCD-chunked, panel-major swizzle (bijective): all N-tiles of one A-panel
    // run consecutively on one XCD -> staging re-reads hit that XCD's L2.
    int nx = gridDim.x, ny = gridDim.y;
    int nwg = nx * ny;
    int bid = blockIdx.y * nx + blockIdx.x;     // dispatch order (x fastest)
    int xcd = bid & 7, slot = bid >> 3;
    int qch = nwg >> 3, rch = nwg & 7;
    int wk = (xcd < rch ? xcd * (qch + 1) : rch * (qch + 1) + (xcd - rch) * qch)
             + slot;
    int bx = wk / ny, by = wk - bx * ny;
    int m0 = bx * 256, n0 = by * 128;

    int wm = (w >> 1) * 64, wn = (w & 1) * 64;

    f32x4 acc[4][4];
#pragma unroll
    for (int i = 0; i < 4; i++)
#pragma unroll
        for (int j = 0; j < 4; j++) acc[i][j] = f32x4{0.f, 0.f, 0.f, 0.f};

    // Staging per K-step: A 1024 slots of 16B (thread t -> slots t, t+512),
    // B 512 slots (thread t -> slot t). 3 loads/thread/step.
    // Bank-conflict swizzle (verified 3.6M -> 0): LDS slot (row,c) receives
    // global chunk c ^ ((row>>1)&3); ds_read XORs the same term back.
    int swzc = ((tid & 3) ^ ((tid >> 3) & 3)) * 8;   // same for t and t+512
    int ar0 = tid >> 2;                               // A rows: ar0, ar0+128
    const bf16* Ag0 = A + (size_t)(m0 + ar0) * K + swzc;
    const bf16* Ag1 = A + (size_t)(m0 + ar0 + 128) * K + swzc;
    const bf16* Bg0 = Bt + (size_t)(n0 + ar0) * K + swzc;
    char* aw = (char*)As + (size_t)w * 1024;         // wave's linear DMA dest
    char* bw = (char*)Bs + (size_t)w * 1024;

    int q = l >> 4, r = l & 15;
    int qs = (q ^ ((r >> 1) & 3)) * 8;               // swizzled read column

    auto stage = [&](int buf, int kt) {
        int kk = kt * 32;
        char* ad = aw + buf * 16384;
        char* bd = bw + buf * 8192;
        gld16(Ag0 + kk, ad);
        gld16(Ag1 + kk, ad + 8192);
        gld16(Bg0 + kk, bd);
    };
    // mfma(bfr, af): lane (q,r) holds output row wm+mi*16+r,
    // cols wn+ni*16+q*4..+3 -> vectorized epilogue.
    auto compute = [&](int buf) {
        const bf16* Ax = &As[0][0] + buf * 8192;
        const bf16* Bx = &Bs[0][0] + buf * 4096;
        bf16x8 af[4], bfr[4];
#pragma unroll
        for (int mi = 0; mi < 4; mi++)
            af[mi] = *(const bf16x8*)&Ax[(wm + mi * 16 + r) * 32 + qs];
#pragma unroll
        for (int ni = 0; ni < 4; ni++)
            bfr[ni] = *(const bf16x8*)&Bx[(wn + ni * 16 + r) * 32 + qs];
        __builtin_amdgcn_s_setprio(1);
#pragma unroll
        for (int mi = 0; mi < 4; mi++)
#pragma unroll
            for (int ni = 0; ni < 4; ni++)
                acc[mi][ni] = __builtin_amdgcn_mfma_f32_16x16x32_bf16(
                    bfr[ni], af[mi], acc[mi][ni], 0, 0, 0);
        __builtin_amdgcn_s_setprio(0);
    };

    // 3-deep circular pipeline, counted vmcnt: tile t+2 issued right after the
    // iter-t barrier, waited two compute-phases later. 3 loads/thread/stage ->
    // vmcnt(3) leaves the newest tile's loads in flight across the barrier.
    const int nk = K >> 5;                 // 12 or 48
    stage(0, 0);
    stage(1, 1);
    int cb = 0, nb = 2;
    for (int t = 0; t < nk - 2; ++t) {
        asm volatile("s_waitcnt vmcnt(3)" ::: "memory");
        __builtin_amdgcn_s_barrier();
        stage(nb, t + 2);
        compute(cb);
        cb = (cb == 2) ? 0 : cb + 1;
        nb = (nb == 2) ? 0 : nb + 1;
    }
    asm volatile("s_waitcnt vmcnt(3)" ::: "memory");
    __builtin_amdgcn_s_barrier();
    compute(cb);
    cb = (cb == 2) ? 0 : cb + 1;
    asm volatile("s_waitcnt vmcnt(0)" ::: "memory");
    __builtin_amdgcn_s_barrier();
    compute(cb);

    // epilogue: rows wm+mi*16+r (4/thread), cols wn+ni*16+q*4..+3 (4 groups)
#pragma unroll
    for (int mi = 0; mi < 4; mi++) {
        int grow = m0 + wm + mi * 16 + r;       // chunk-local output row
        size_t rowbase;
        if (mode == GM_PROJ) {
            int growg = m_base + grow;
            int wi = growg / 49, n = growg - wi * 49;
            int b_ = wi >> 6, w64 = wi & 63;
            int wy = w64 >> 3, wx = w64 & 7;
            int pin = n / 7, qin = n - pin * 7;
            int hs = wy * 7 + pin + shift; if (hs >= 56) hs -= 56;
            int ws2 = wx * 7 + qin + shift; if (ws2 >= 56) ws2 -= 56;
            rowbase = ((size_t)b_ * 3136 + hs * 56 + ws2) * CDIM;
        } else if (mode == GM_QKV || mode == GM_FC1) {
            rowbase = (size_t)grow * Nout;
        } else {
            rowbase = (size_t)(m_base + grow) * CDIM;
        }
#pragma unroll
        for (int ni = 0; ni < 4; ni++) {
            int gc0 = n0 + wn + ni * 16 + q * 4;
            const f32x4 bv = *(const f32x4*)&bias[gc0];
            f32x4 vv;
#pragma unroll
            for (int rr = 0; rr < 4; rr++) vv[rr] = acc[mi][ni][rr] + bv[rr];
            if (mode == GM_QKV) {
                store4bf(obf + rowbase + gc0, vv);
            } else if (mode == GM_FC1) {
#pragma unroll
                for (int rr = 0; rr < 4; rr++) {
                    float v = vv[rr];
                    // tanh-form GELU: |err| < 4e-4, below bf16 rounding.
                    float u = v * (0.7978845608028654f
                                   + 0.0356774081363001f * v * v);
                    float t = 1.f - 2.f / (1.f + __expf(2.f * u));
                    vv[rr] = 0.5f * v * (1.f + t);
                }
                store4bf(obf + rowbase + gc0, vv);
            } else if (mode == GM_PROJ) {
                const f32x4 sc = *(const f32x4*)(shortcut + rowbase + gc0);
#pragma unroll
                for (int rr = 0; rr < 4; rr++) vv[rr] += sc[rr];
                *(f32x4*)(xres + rowbase + gc0) = vv;
            } else {
                const f32x4 old = *(const f32x4*)(xres + rowbase + gc0);
#pragma unroll
                for (int rr = 0; rr < 4; rr++) vv[rr] += old[rr];
                if (mode == GM_FC2) *(f32x4*)(xres + rowbase + gc0) = vv;
                else *(f32x4*)(ofinal + rowbase + gc0) = vv;  // fp32 final out
            }
        }
    }
}

// ---------------- windowed attention v2: wave per (window,head), 4 waves/block ----
__device__ __forceinline__ int regionof(int p) {
    return (p < 49) ? 0 : (p < 53 ? 1 : 2);
}

__global__ __launch_bounds__(256) void k_attn(const bf16* __restrict__ qkv,
                                              const float* __restrict__ rpb,
                                              bf16* __restrict__ out, int shift,
                                              int wi0) {
    __shared__ float kv[4][2][49 * 32];   // [wave][k/v] = 50176 B total
    int wave = threadIdx.x >> 6, l = threadIdx.x & 63;
    int p = blockIdx.x * 4 + wave;        // chunk-local (window,head) pair
    int wl = p / 12, h = p - wl * 12;
    int wig = wi0 + wl;
    float* ks = kv[wave][0];
    float* vs = kv[wave][1];

    const bf16* base = qkv + (size_t)wl * 49 * 1152 + h * 32;
#pragma unroll
    for (int it = 0; it < 25; it++) {
        int idx = l + it * 64;
        if (idx < 1568) {
            int n = idx >> 5, d = idx & 31;
            size_t ro = (size_t)n * 1152 + d;
            ks[idx] = __bfloat162float(base[ro + 384]);
            vs[idx] = __bfloat162float(base[ro + 768]);
        }
    }
    int active = (l < 49);
    int le = active ? l : 0;
    float qreg[32];
    const bf16* qrow = base + (size_t)le * 1152;
#pragma unroll
    for (int d = 0; d < 32; d++) qreg[d] = __bfloat162float(qrow[d]) * SCALE;
    __syncthreads();

    int pin = le / 7, qin = le - (le / 7) * 7;
    int w64 = wig & 63;
    int py = (w64 >> 3) * 7, px = (w64 & 7) * 7;
    int regq = regionof(py + pin) * 3 + regionof(px + qin);

    float srow[49];
    float mx = -1e30f;
#pragma unroll
    for (int m = 0; m < 49; m++) {
        const float* kr = &ks[m * 32];
        float s = 0.f;
#pragma unroll
        for (int d = 0; d < 32; d++) s += qreg[d] * kr[d];
        const int mp = m / 7, mq = m - (m / 7) * 7;
        s += rpb[((pin - mp + 6) * 13 + (qin - mq + 6)) * 12 + h];
        if (shift > 0) {
            int regm = regionof(py + mp) * 3 + regionof(px + mq);
            if (regm != regq) s -= 100.f;
        }
        srow[m] = s;
        mx = fmaxf(mx, s);
    }
    float sum = 0.f;
#pragma unroll
    for (int m = 0; m < 49; m++) {
        float e = __expf(srow[m] - mx);
        srow[m] = e;
        sum += e;
    }
    float inv = 1.f / sum;

    float o[32];
#pragma unroll
    for (int d = 0; d < 32; d++) o[d] = 0.f;
#pragma unroll
    for (int m = 0; m < 49; m++) {
        const float* vr = &vs[m * 32];
        float pm = srow[m];
#pragma unroll
        for (int d = 0; d < 32; d++) o[d] += pm * vr[d];
    }
    if (active) {
        bf16* op = out + ((size_t)wl * 49 + l) * 384 + h * 32;
#pragma unroll
        for (int d = 0; d < 32; d++) op[d] = __float2bfloat16(o[d] * inv);
    }
}

// ---------------- host launch ----------------
extern "C" void kernel_launch(void* const* d_in, const int* in_sizes, int n_in,
                              void* d_out, int out_size, void* d_ws, size_t ws_size,
                              hipStream_t stream) {
    const float* x       = (const float*)d_in[0];
    const float* norm1_g = (const float*)d_in[1];
    const float* norm1_b = (const float*)d_in[2];
    const float* qkv_w   = (const float*)d_in[3];
    const float* qkv_b   = (const float*)d_in[4];
    const float* rpb     = (const float*)d_in[5];
    const float* proj_w  = (const float*)d_in[6];
    const float* proj_b  = (const float*)d_in[7];
    const float* norm2_g = (const float*)d_in[8];
    const float* norm2_b = (const float*)d_in[9];
    const float* fc1_w   = (const float*)d_in[10];
    const float* fc1_b   = (const float*)d_in[11];
    const float* fc2_w   = (const float*)d_in[12];
    const float* fc2_b   = (const float*)d_in[13];
    (void)in_sizes; (void)n_in; (void)out_size;

    int nc = (ws_size >= (size_t)199753728) ? 2 : 4;
    int rows = TOK / nc;               // 25088 or 12544 (both /256 integral)
    int wins = rows / 49;              // 512 or 256
    size_t arena_sz = (size_t)rows * 1152 * 2 + (size_t)rows * 384 * 2;

    float* xres  = (float*)d_ws;                              // 77,070,336 B
    bf16* lnbuf  = (bf16*)((char*)d_ws + 77070336);           // 38,535,168 B
    char* arena  = (char*)d_ws + 115605504;                   // arena_sz B
    bf16* wT     = (bf16*)((char*)d_ws + 115605504 + arena_sz); // 7,077,888 B

    bf16* qkvbuf  = (bf16*)arena;
    bf16* attnbuf = (bf16*)(arena + (size_t)rows * 1152 * 2);
    bf16* fc1buf  = (bf16*)arena;     // rows*1536*2 <= rows*1152*2 + rows*384*2

    bf16* qkvT  = wT;                          // 2 x 1152*384
    bf16* projT = wT + 884736;                 // 2 x 384*384
    bf16* fc1T  = projT + 294912;              // 2 x 1536*384
    bf16* fc2T  = fc1T + 1179648;              // 2 x 384*1536

    for (int i = 0; i < 2; i++) {
        k_transpose<<<(384 * 1152 + 255) / 256, 256, 0, stream>>>(
            qkv_w + (size_t)i * 442368, qkvT + (size_t)i * 442368, 384, 1152);
        k_transpose<<<(384 * 384 + 255) / 256, 256, 0, stream>>>(
            proj_w + (size_t)i * 147456, projT + (size_t)i * 147456, 384, 384);
        k_transpose<<<(384 * 1536 + 255) / 256, 256, 0, stream>>>(
            fc1_w + (size_t)i * 589824, fc1T + (size_t)i * 589824, 384, 1536);
        k_transpose<<<(1536 * 384 + 255) / 256, 256, 0, stream>>>(
            fc2_w + (size_t)i * 589824, fc2T + (size_t)i * 589824, 1536, 384);
    }

    for (int i = 0; i < 2; i++) {
        int shift = (i == 0) ? 0 : 3;
        // block 0 reads the input x directly (xres not yet materialized);
        // proj's epilogue then writes xres = x + o, eliminating the k_cvt copy.
        const float* resid = (i == 0) ? x : xres;
        k_ln<<<TOK / 4, 256, 0, stream>>>(resid, norm1_g + i * 384, norm1_b + i * 384,
                                          lnbuf, shift, 1);
        for (int c = 0; c < nc; c++) {
            const bf16* Ac = lnbuf + (size_t)c * rows * 384;
            k_gemm<<<dim3(rows / 256, 9), 512, 0, stream>>>(
                Ac, qkvT + (size_t)i * 442368, qkv_b + i * 1152, 384, 1152,
                qkvbuf, nullptr, nullptr, nullptr, GM_QKV, 0, 0);
            k_attn<<<wins * 12 / 4, 256, 0, stream>>>(qkvbuf, rpb + i * 2028,
                                                      attnbuf, shift, c * wins);
            k_gemm<<<dim3(rows / 256, 3), 512, 0, stream>>>(
                attnbuf, projT + (size_t)i * 147456, proj_b + i * 384, 384, 384,
                nullptr, xres, nullptr, resid, GM_PROJ, shift, c * rows);
        }
        k_ln<<<TOK / 4, 256, 0, stream>>>(xres, norm2_g + i * 384, norm2_b + i * 384,
                                          lnbuf, 0, 0);
        for (int c = 0; c < nc; c++) {
            const bf16* Ac = lnbuf + (size_t)c * rows * 384;
            k_gemm<<<dim3(rows / 256, 12), 512, 0, stream>>>(
                Ac, fc1T + (size_t)i * 589824, fc1_b + i * 1536, 384, 1536,
                fc1buf, nullptr, nullptr, nullptr, GM_FC1, 0, 0);
            k_gemm<<<dim3(rows / 256, 3), 512, 0, stream>>>(
                fc1buf, fc2T + (size_t)i * 589824, fc2_b + i * 384, 1536, 384,
                nullptr, xres, (float*)d_out, nullptr,
                (i == 0) ? GM_FC2 : GM_FC2OUT, 0, c * rows);
        }
    }
}